// Round 11
// baseline (29.231 us; speedup 1.0000x reference)
//
#include <hip/hip_runtime.h>
#include <math.h>

#define BB 32
#define TT 50
#define HH 52
#define WW 52
#define NB 3
#define NC 80
#define CE 85            // 5 + NC
#define SP (HH*WW)       // 2704
#define NCELL (BB*NB*SP) // 259584
#define NT (BB*TT)       // 1600 targets
#define EPSF 1e-7f

#define NBLK 507         // NCELL / (256 threads * 2 cells) exactly
#define POSBLK 100       // NT / (4 waves * 4 targets-per-wave)

__device__ __forceinline__ float sigc(float z) {
    float p = 1.0f / (1.0f + expf(-z));
    return fminf(fmaxf(p, EPSF), 1.0f - EPSF);
}

// bce(sigmoid(z), 0) = log(1 + e^z), numerically robust form.
__device__ __forceinline__ float softplus(float z) {
    return fmaxf(z, 0.0f) + log1pf(expf(-fabsf(z)));
}

__device__ __forceinline__ unsigned getbit(unsigned m0, unsigned m1, unsigned m2, int c) {
    return (c < 32) ? ((m0 >> c) & 1u)
         : (c < 64) ? ((m1 >> (c - 32)) & 1u)
                    : ((m2 >> (c - 64)) & 1u);
}

// coherent read: returning RMW (+0.0) executes at the coherent point
__device__ __forceinline__ float crd(float* p) { return atomicAdd(p, 0.0f); }

// anchor match for target w; returns packed (cell<<7)|class or -1.
// Division-free argmax: a/b > c/d  <=>  a*d > c*b for positive b,d.
__device__ __forceinline__ int match_target(const float* __restrict__ xywh,
                                            const int* __restrict__ cls,
                                            int i, int w,
                                            float* obx, float* oby,
                                            float* obw, float* obh, int* oaid) {
    const float A[18] = {10,13,16,30,33,23,30,61,62,45,59,119,116,90,156,198,373,326};
    float bx = xywh[w*4+0] * WW, by = xywh[w*4+1] * HH;
    float bw = xywh[w*4+2] * WW, bh = xywh[w*4+3] * HH;
    int aid = 0;
    float bi = -1.0f, bu = 1.0f;          // best inter/union as a ratio pair
    #pragma unroll
    for (int k = 0; k < 9; ++k) {
        float aw = A[2*k] * 0.125f, ah = A[2*k+1] * 0.125f;  // ANCHORS/(416/52)
        float inter = fminf(bw, aw) * fminf(bh, ah);
        float uni = bw * bh + aw * ah - inter;
        if (inter * bu > bi * uni) { bi = inter; bu = uni; aid = k; }
    }
    *obx = bx; *oby = by; *obw = bw; *obh = bh; *oaid = aid;
    int gx = (int)floorf(bx), gy = (int)floorf(by);
    if ((aid / 3) == (2 - i) && gx >= 0 && gx < WW && gy >= 0 && gy < HH) {
        int b = w / TT;
        int cell = ((b * NB + (aid % 3)) * HH + gy) * WW + gx;
        return (cell << 7) | cls[w];
    }
    return -1;
}

// Single kernel: dense conf + positive loss + last-done-block finalize.
// Counters zeroed by a 64B memset node each call; exact-count election
// (sub-counter per bid&7 feeding a master), publishes via RETURNING
// atomicExch (sc0 round-trip) ordered before counter adds by vmcnt(0).
__global__ void __launch_bounds__(256)
k_main(const float* __restrict__ pred,
       const float* __restrict__ xywh,
       const int* __restrict__ cls,
       const int* __restrict__ pi,
       unsigned* __restrict__ cnt_sub,   // [8]  zeroed each call
       unsigned* __restrict__ cnt_mst,   // [1]  zeroed each call
       float* __restrict__ confpart,     // [NBLK]
       float* __restrict__ pospart,      // [POSBLK][8]
       float* __restrict__ out) {
    __shared__ int epack[NT];
    __shared__ float sred[4];
    __shared__ float pred_red[4][8];
    __shared__ float fred[4][7];
    __shared__ unsigned slast;
    int tid = threadIdx.x;
    int bid = blockIdx.x;
    int lane = tid & 63;
    int wid = tid >> 6;

    // --- dense conf, assume negative: bce(sigmoid(z), 0) = softplus(z) ---
    int base = (bid * 256 + tid) * 2;
    int ba = base / SP, sp = base % SP;
    float2 z2 = *(const float2*)(pred + ((size_t)ba * CE + 4) * SP + sp);
    float vconf = softplus(z2.x) + softplus(z2.y);

    // --- positive phase ---
    if (bid < POSBLK) {
        int i = *pi;
        // phase 1: build match table in LDS (identical in all pos blocks)
        for (int w = tid; w < NT; w += 256) {
            float bx, by, bw, bh; int aid;
            epack[w] = match_target(xywh, cls, i, w, &bx, &by, &bw, &bh, &aid);
        }
        __syncthreads();

        // phase 2a: prefetch channel gathers for all 4 targets
        float zprim[4], zsec[4];
        bool tval[4];
        #pragma unroll
        for (int t = 0; t < 4; ++t) {
            int wv = bid * 16 + wid * 4 + t;
            int ep = epack[wv];
            tval[t] = (ep >= 0);
            zprim[t] = 0.0f; zsec[t] = 0.0f;
            if (ep >= 0) {                     // wave-uniform
                int cell = ep >> 7;
                int cba = cell / SP, csp = cell % SP;
                const float* pc = pred + (size_t)cba * CE * SP + csp;
                zprim[t] = pc[lane * SP];
                if (lane < CE - 64) zsec[t] = pc[(64 + lane) * SP];
            }
        }

        // phase 2b: dedup scan + loss per target on prefetched values
        float acc[7] = {0.f, 0.f, 0.f, 0.f, 0.f, 0.f, 0.f}; // lx,ly,lw,lh,dconf,cls,cnt
        #pragma unroll
        for (int t = 0; t < 4; ++t) {
            if (!tval[t]) continue;            // wave-uniform branch
            int wv = bid * 16 + wid * 4 + t;
            int cell = epack[wv] >> 7;
            unsigned m0 = 0, m1 = 0, m2 = 0;
            int mx = -1;
            #pragma unroll
            for (int k = 0; k < NT / 64; ++k) {
                int e = lane + 64 * k;
                int ee = epack[e];
                if (ee >= 0 && (ee >> 7) == cell) {
                    int c = ee & 127;
                    if (c < 32) m0 |= 1u << c;
                    else if (c < 64) m1 |= 1u << (c - 32);
                    else m2 |= 1u << (c - 64);
                    mx = max(mx, e);
                }
            }
            #pragma unroll
            for (int off = 32; off; off >>= 1) {
                m0 |= __shfl_xor(m0, off);
                m1 |= __shfl_xor(m1, off);
                m2 |= __shfl_xor(m2, off);
                mx = max(mx, __shfl_xor(mx, off));
            }
            if (mx != wv) continue;            // not the winner (wave-uniform)

            const float A[18] = {10,13,16,30,33,23,30,61,62,45,59,119,116,90,156,198,373,326};
            float bx, by, bw, bh; int aid;
            (void)match_target(xywh, cls, i, wv, &bx, &by, &bw, &bh, &aid);
            float aw = A[2*aid] * 0.125f, ah = A[2*aid+1] * 0.125f;
            float gx = floorf(bx), gy = floorf(by);
            float tx = bx - gx, ty = by - gy;
            float tw = logf(bw / aw), th = logf(bh / ah);
            float scale = 2.0f - bw * bh / (float)(HH * WW);

            float z = zprim[t];
            float p = sigc(z);
            float prim;
            if (lane == 0)      prim = (-tx * logf(p) - (1.0f - tx) * logf(1.0f - p)) * scale;
            else if (lane == 1) prim = (-ty * logf(p) - (1.0f - ty) * logf(1.0f - p)) * scale;
            else if (lane == 2) { float d = z - tw; prim = d * d * scale; }
            else if (lane == 3) { float d = z - th; prim = d * d * scale; }
            else if (lane == 4) prim = -logf(p) + logf(1.0f - p);  // bce(p,1)-bce(p,0)
            else {
                int c = lane - 5;  // class 0..58
                prim = getbit(m0, m1, m2, c) ? -logf(p) : -logf(1.0f - p);
            }
            float sec = 0.0f;
            if (lane < CE - 64) {   // channels 64..84 -> classes 59..79
                float pc2 = sigc(zsec[t]);
                sec = getbit(m0, m1, m2, 59 + lane) ? -logf(pc2) : -logf(1.0f - pc2);
            }
            float clsv = (lane >= 5 ? prim : 0.0f) + sec;
            #pragma unroll
            for (int off = 32; off; off >>= 1) clsv += __shfl_xor(clsv, off);
            acc[0] += __shfl(prim, 0);
            acc[1] += __shfl(prim, 1);
            acc[2] += __shfl(prim, 2);
            acc[3] += __shfl(prim, 3);
            acc[4] += __shfl(prim, 4);
            acc[5] += clsv;
            acc[6] += 1.0f;
        }
        // cross-wave reduce -> publish one row via RETURNING exchanges
        if (lane == 0) {
            #pragma unroll
            for (int k = 0; k < 7; ++k) pred_red[wid][k] = acc[k];
        }
        __syncthreads();
        if (tid == 0) {
            float sink = 0.0f;
            #pragma unroll
            for (int k = 0; k < 7; ++k) {
                float r = pred_red[0][k] + pred_red[1][k] + pred_red[2][k] + pred_red[3][k];
                sink += atomicExch(&pospart[bid * 8 + k], r);  // sc0 (old used)
            }
            asm volatile("" :: "v"(sink));   // keep olds live -> forces sc0
        }
    }

    // --- block-reduce dense conf ---
    #pragma unroll
    for (int off = 32; off; off >>= 1) vconf += __shfl_down(vconf, off);
    if (lane == 0) sred[wid] = vconf;
    __syncthreads();

    // --- publish conf partial, exact two-level last-block election ---
    if (tid == 0) {
        float cp = sred[0] + sred[1] + sred[2] + sred[3];
        float old = atomicExch(&confpart[bid], cp);      // sc0 (old used)
        asm volatile("" :: "v"(old));
        asm volatile("s_waitcnt vmcnt(0)" ::: "memory"); // publishes at coherent pt
        int j = bid & 7;
        unsigned quota = (j < 3) ? 64u : 63u;            // 507 = 3*64 + 5*63
        unsigned o = atomicAdd(&cnt_sub[j], 1u);
        unsigned last = 0u;
        if (o == quota - 1u) {                           // sub-last of residue j
            asm volatile("s_waitcnt vmcnt(0)" ::: "memory");
            unsigned om = atomicAdd(cnt_mst, 1u);
            last = (om == 7u) ? 1u : 0u;                 // 8th sub-last: all done
        }
        slast = last;
    }
    __syncthreads();

    // --- last-done block finalizes (coherent RMW reads, R8 k_final order) ---
    if (slast) {
        float v[7] = {0.f, 0.f, 0.f, 0.f, 0.f, 0.f, 0.f};  // conf,lx,ly,lw,lh,cls,cnt
        for (int r = tid; r < NBLK; r += 256) v[0] += crd(&confpart[r]);
        if (tid < POSBLK) {
            v[1] += crd(&pospart[tid * 8 + 0]);
            v[2] += crd(&pospart[tid * 8 + 1]);
            v[3] += crd(&pospart[tid * 8 + 2]);
            v[4] += crd(&pospart[tid * 8 + 3]);
            v[0] += crd(&pospart[tid * 8 + 4]);
            v[5] += crd(&pospart[tid * 8 + 5]);
            v[6] += crd(&pospart[tid * 8 + 6]);
        }
        #pragma unroll
        for (int off = 32; off; off >>= 1) {
            #pragma unroll
            for (int k = 0; k < 7; ++k) v[k] += __shfl_down(v[k], off);
        }
        if (lane == 0) {
            #pragma unroll
            for (int k = 0; k < 7; ++k) fred[wid][k] = v[k];
        }
        __syncthreads();
        if (tid == 0) {
            float conf_s = fred[0][0] + fred[1][0] + fred[2][0] + fred[3][0];
            float lxs    = fred[0][1] + fred[1][1] + fred[2][1] + fred[3][1];
            float lys    = fred[0][2] + fred[1][2] + fred[2][2] + fred[3][2];
            float lws    = fred[0][3] + fred[1][3] + fred[2][3] + fred[3][3];
            float lhs    = fred[0][4] + fred[1][4] + fred[2][4] + fred[3][4];
            float cls_s  = fred[0][5] + fred[1][5] + fred[2][5] + fred[3][5];
            float pos    = fred[0][6] + fred[1][6] + fred[2][6] + fred[3][6];

            float den = fmaxf(pos, 1.0f);
            float loc = (lxs + lys + lws + lhs) / den * 0.1f;
            float clsL = cls_s / (den * (float)NC);
            int i = *pi;
            float bal = (i == 0) ? 0.4f : (i == 1) ? 1.0f : 4.0f;
            float conf = conf_s / (float)NCELL * bal;
            bool has = pos > 0.0f;
            float total = (has ? (loc * 0.05f + clsL * 0.5f) : 0.0f) + conf;
            out[0] = total;
            out[1] = conf;
            out[2] = has ? loc : 0.0f;
            out[3] = has ? clsL : 0.0f;
        }
    }
}

extern "C" void kernel_launch(void* const* d_in, const int* in_sizes, int n_in,
                              void* d_out, int out_size, void* d_ws, size_t ws_size,
                              hipStream_t stream) {
    const int*   pi   = (const int*)d_in[0];
    const float* pred = (const float*)d_in[1];
    const float* xywh = (const float*)d_in[2];
    const int*   cls  = (const int*)d_in[3];
    float* out = (float*)d_out;

    char* ws = (char*)d_ws;
    unsigned* cnt_sub  = (unsigned*)ws;               // 8 uints
    unsigned* cnt_mst  = (unsigned*)(ws + 32);        // 1 uint
    float*    confpart = (float*)(ws + 256);          // NBLK floats
    float*    pospart  = (float*)(ws + 4096);         // POSBLK*8 floats

    hipMemsetAsync(ws, 0, 64, stream);                // zero both counters
    k_main<<<NBLK, 256, 0, stream>>>(pred, xywh, cls, pi,
                                     cnt_sub, cnt_mst, confpart, pospart, out);
}

// Round 12
// 19.340 us; speedup vs baseline: 1.5114x; 1.5114x over previous
//
#include <hip/hip_runtime.h>
#include <math.h>

#define BB 32
#define TT 50
#define HH 52
#define WW 52
#define NB 3
#define NC 80
#define CE 85            // 5 + NC
#define SP (HH*WW)       // 2704
#define NCELL (BB*NB*SP) // 259584
#define NT (BB*TT)       // 1600 targets
#define EPSF 1e-7f

#define NBLK 507         // NCELL / (256 threads * 2 cells) exactly
#define POSBLK 100       // NT / (4 waves * 4 targets-per-wave)

__device__ __forceinline__ float sigc(float z) {
    float p = 1.0f / (1.0f + expf(-z));
    return fminf(fmaxf(p, EPSF), 1.0f - EPSF);
}

// bce(sigmoid(z), 0) = log(1 + e^z), numerically robust form.
__device__ __forceinline__ float softplus(float z) {
    return fmaxf(z, 0.0f) + log1pf(expf(-fabsf(z)));
}

__device__ __forceinline__ unsigned getbit(unsigned m0, unsigned m1, unsigned m2, int c) {
    return (c < 32) ? ((m0 >> c) & 1u)
         : (c < 64) ? ((m1 >> (c - 32)) & 1u)
                    : ((m2 >> (c - 64)) & 1u);
}

// anchor match for target w; returns packed (cell<<7)|class or -1.
// Division-free argmax: a/b > c/d  <=>  a*d > c*b for positive b,d.
__device__ __forceinline__ int match_target(const float* __restrict__ xywh,
                                            const int* __restrict__ cls,
                                            int i, int w,
                                            float* obx, float* oby,
                                            float* obw, float* obh, int* oaid) {
    const float A[18] = {10,13,16,30,33,23,30,61,62,45,59,119,116,90,156,198,373,326};
    float bx = xywh[w*4+0] * WW, by = xywh[w*4+1] * HH;
    float bw = xywh[w*4+2] * WW, bh = xywh[w*4+3] * HH;
    int aid = 0;
    float bi = -1.0f, bu = 1.0f;          // best inter/union as a ratio pair
    #pragma unroll
    for (int k = 0; k < 9; ++k) {
        float aw = A[2*k] * 0.125f, ah = A[2*k+1] * 0.125f;  // ANCHORS/(416/52)
        float inter = fminf(bw, aw) * fminf(bh, ah);
        float uni = bw * bh + aw * ah - inter;
        if (inter * bu > bi * uni) { bi = inter; bu = uni; aid = k; }
    }
    *obx = bx; *oby = by; *obw = bw; *obh = bh; *oaid = aid;
    int gx = (int)floorf(bx), gy = (int)floorf(by);
    if ((aid / 3) == (2 - i) && gx >= 0 && gx < WW && gy >= 0 && gy < HH) {
        int b = w / TT;
        int cell = ((b * NB + (aid % 3)) * HH + gy) * WW + gx;
        return (cell << 7) | cls[w];
    }
    return -1;
}

// Fused kernel: dense negative-conf over all cells (2 cells/thread, float2) +
// positive-cell loss on blocks 0..POSBLK-1 (4 waves x 4 targets each,
// with all channel gathers prefetched before the dedup scans).
__global__ void __launch_bounds__(256)
k_main(const float* __restrict__ pred,
       const float* __restrict__ xywh,
       const int* __restrict__ cls,
       const int* __restrict__ pi,
       float* __restrict__ confpart,   // [NBLK]
       float* __restrict__ pospart) {  // [POSBLK][8]
    __shared__ int epack[NT];
    __shared__ float sred[4];
    __shared__ float pred_red[4][8];
    int tid = threadIdx.x;
    int bid = blockIdx.x;
    int lane = tid & 63;
    int wid = tid >> 6;

    // --- dense conf, assume negative: bce(sigmoid(z), 0) = softplus(z) ---
    int base = (bid * 256 + tid) * 2;
    int ba = base / SP, sp = base % SP;
    float2 z2 = *(const float2*)(pred + ((size_t)ba * CE + 4) * SP + sp);
    float vconf = softplus(z2.x) + softplus(z2.y);

    // --- positive phase ---
    if (bid < POSBLK) {
        int i = *pi;
        // phase 1: build match table in LDS (identical in all pos blocks)
        for (int w = tid; w < NT; w += 256) {
            float bx, by, bw, bh; int aid;
            epack[w] = match_target(xywh, cls, i, w, &bx, &by, &bw, &bh, &aid);
        }
        __syncthreads();

        // phase 2a: prefetch channel gathers for all 4 targets (addresses
        // depend only on epack; loads fly while the scans below execute).
        float zprim[4], zsec[4];
        bool tval[4];
        #pragma unroll
        for (int t = 0; t < 4; ++t) {
            int wv = bid * 16 + wid * 4 + t;
            int ep = epack[wv];
            tval[t] = (ep >= 0);
            zprim[t] = 0.0f; zsec[t] = 0.0f;
            if (ep >= 0) {                     // wave-uniform
                int cell = ep >> 7;
                int cba = cell / SP, csp = cell % SP;
                const float* pc = pred + (size_t)cba * CE * SP + csp;
                zprim[t] = pc[lane * SP];
                if (lane < CE - 64) zsec[t] = pc[(64 + lane) * SP];
            }
        }

        // phase 2b: dedup scan + loss per target on prefetched values
        float acc[7] = {0.f, 0.f, 0.f, 0.f, 0.f, 0.f, 0.f}; // lx,ly,lw,lh,dconf,cls,cnt
        #pragma unroll
        for (int t = 0; t < 4; ++t) {
            if (!tval[t]) continue;            // wave-uniform branch
            int wv = bid * 16 + wid * 4 + t;
            int cell = epack[wv] >> 7;
            unsigned m0 = 0, m1 = 0, m2 = 0;
            int mx = -1;
            #pragma unroll
            for (int k = 0; k < NT / 64; ++k) {
                int e = lane + 64 * k;
                int ee = epack[e];
                if (ee >= 0 && (ee >> 7) == cell) {
                    int c = ee & 127;
                    if (c < 32) m0 |= 1u << c;
                    else if (c < 64) m1 |= 1u << (c - 32);
                    else m2 |= 1u << (c - 64);
                    mx = max(mx, e);
                }
            }
            #pragma unroll
            for (int off = 32; off; off >>= 1) {
                m0 |= __shfl_xor(m0, off);
                m1 |= __shfl_xor(m1, off);
                m2 |= __shfl_xor(m2, off);
                mx = max(mx, __shfl_xor(mx, off));
            }
            if (mx != wv) continue;            // not the winner (wave-uniform)

            const float A[18] = {10,13,16,30,33,23,30,61,62,45,59,119,116,90,156,198,373,326};
            float bx, by, bw, bh; int aid;
            (void)match_target(xywh, cls, i, wv, &bx, &by, &bw, &bh, &aid);
            float aw = A[2*aid] * 0.125f, ah = A[2*aid+1] * 0.125f;
            float gx = floorf(bx), gy = floorf(by);
            float tx = bx - gx, ty = by - gy;
            float tw = logf(bw / aw), th = logf(bh / ah);
            float scale = 2.0f - bw * bh / (float)(HH * WW);

            float z = zprim[t];
            float p = sigc(z);
            float prim;
            if (lane == 0)      prim = (-tx * logf(p) - (1.0f - tx) * logf(1.0f - p)) * scale;
            else if (lane == 1) prim = (-ty * logf(p) - (1.0f - ty) * logf(1.0f - p)) * scale;
            else if (lane == 2) { float d = z - tw; prim = d * d * scale; }
            else if (lane == 3) { float d = z - th; prim = d * d * scale; }
            else if (lane == 4) prim = -logf(p) + logf(1.0f - p);  // bce(p,1)-bce(p,0)
            else {
                int c = lane - 5;  // class 0..58
                prim = getbit(m0, m1, m2, c) ? -logf(p) : -logf(1.0f - p);
            }
            float sec = 0.0f;
            if (lane < CE - 64) {   // channels 64..84 -> classes 59..79
                float pc2 = sigc(zsec[t]);
                sec = getbit(m0, m1, m2, 59 + lane) ? -logf(pc2) : -logf(1.0f - pc2);
            }
            float clsv = (lane >= 5 ? prim : 0.0f) + sec;
            #pragma unroll
            for (int off = 32; off; off >>= 1) clsv += __shfl_xor(clsv, off);
            acc[0] += __shfl(prim, 0);
            acc[1] += __shfl(prim, 1);
            acc[2] += __shfl(prim, 2);
            acc[3] += __shfl(prim, 3);
            acc[4] += __shfl(prim, 4);
            acc[5] += clsv;
            acc[6] += 1.0f;
        }
        // cross-wave reduce (acc is wave-uniform) -> one row per block
        if (lane == 0) {
            #pragma unroll
            for (int k = 0; k < 7; ++k) pred_red[wid][k] = acc[k];
        }
        __syncthreads();
        if (tid == 0) {
            float r[7];
            #pragma unroll
            for (int k = 0; k < 7; ++k)
                r[k] = pred_red[0][k] + pred_red[1][k] + pred_red[2][k] + pred_red[3][k];
            float4 a = make_float4(r[0], r[1], r[2], r[3]);
            float4 b = make_float4(r[4], r[5], r[6], 0.0f);
            *(float4*)(pospart + bid * 8)     = a;
            *(float4*)(pospart + bid * 8 + 4) = b;
        }
    }

    // --- block-reduce dense conf ---
    #pragma unroll
    for (int off = 32; off; off >>= 1) vconf += __shfl_down(vconf, off);
    if (lane == 0) sred[wid] = vconf;
    __syncthreads();
    if (tid == 0) confpart[bid] = sred[0] + sred[1] + sred[2] + sred[3];
}

__global__ void __launch_bounds__(256)
k_final(const float* __restrict__ confpart,
        const float* __restrict__ pospart,
        const int* __restrict__ pi,
        float* __restrict__ out) {
    int tid = threadIdx.x;
    float v[7] = {0.f, 0.f, 0.f, 0.f, 0.f, 0.f, 0.f};  // conf,lx,ly,lw,lh,cls,cnt
    for (int r = tid; r < NBLK; r += 256) v[0] += confpart[r];
    if (tid < POSBLK) {
        float4 a = *(const float4*)(pospart + tid * 8);
        float4 b = *(const float4*)(pospart + tid * 8 + 4);
        v[1] += a.x; v[2] += a.y; v[3] += a.z; v[4] += a.w;
        v[0] += b.x; v[5] += b.y; v[6] += b.z;
    }
    #pragma unroll
    for (int off = 32; off; off >>= 1) {
        #pragma unroll
        for (int k = 0; k < 7; ++k) v[k] += __shfl_down(v[k], off);
    }
    __shared__ float red[4][7];
    int wid = tid >> 6, lane = tid & 63;
    if (lane == 0) {
        #pragma unroll
        for (int k = 0; k < 7; ++k) red[wid][k] = v[k];
    }
    __syncthreads();
    if (tid == 0) {
        float conf_s = red[0][0] + red[1][0] + red[2][0] + red[3][0];
        float lxs    = red[0][1] + red[1][1] + red[2][1] + red[3][1];
        float lys    = red[0][2] + red[1][2] + red[2][2] + red[3][2];
        float lws    = red[0][3] + red[1][3] + red[2][3] + red[3][3];
        float lhs    = red[0][4] + red[1][4] + red[2][4] + red[3][4];
        float cls_s  = red[0][5] + red[1][5] + red[2][5] + red[3][5];
        float pos    = red[0][6] + red[1][6] + red[2][6] + red[3][6];

        float den = fmaxf(pos, 1.0f);
        float loc = (lxs + lys + lws + lhs) / den * 0.1f;
        float clsL = cls_s / (den * (float)NC);
        int i = *pi;
        float bal = (i == 0) ? 0.4f : (i == 1) ? 1.0f : 4.0f;
        float conf = conf_s / (float)NCELL * bal;
        bool has = pos > 0.0f;
        float total = (has ? (loc * 0.05f + clsL * 0.5f) : 0.0f) + conf;
        out[0] = total;
        out[1] = conf;
        out[2] = has ? loc : 0.0f;
        out[3] = has ? clsL : 0.0f;
    }
}

extern "C" void kernel_launch(void* const* d_in, const int* in_sizes, int n_in,
                              void* d_out, int out_size, void* d_ws, size_t ws_size,
                              hipStream_t stream) {
    const int*   pi   = (const int*)d_in[0];
    const float* pred = (const float*)d_in[1];
    const float* xywh = (const float*)d_in[2];
    const int*   cls  = (const int*)d_in[3];
    float* out = (float*)d_out;

    char* ws = (char*)d_ws;
    float* confpart = (float*)ws;                 // NBLK floats
    float* pospart  = (float*)(ws + 4096);        // POSBLK*8 floats (16B aligned)

    k_main <<<NBLK, 256, 0, stream>>>(pred, xywh, cls, pi, confpart, pospart);
    k_final<<<1, 256, 0, stream>>>(confpart, pospart, pi, out);
}